// Round 2
// baseline (161.322 us; speedup 1.0000x reference)
//
#include <hip/hip_runtime.h>

#define G 64
#define C 32
#define D 18432
#define TDI 64          // cols per LDS sub-tile
#define TDIP 68         // padded row stride (floats); 68*4B rows are 16B-aligned,
                        // and 4*r mod 32 tiles banks exactly for 8 consecutive rows
#define EPS 1e-5f
#define NS_ITERS 5

// ---------------------------------------------------------------------------
// K1: per (group, chunk): partial Gram  P = Z_chunk * Z_chunk^T  (32x32)
//     and partial row sums (32). Row-major LDS tile, float4 fragments along d.
// ---------------------------------------------------------------------------
__global__ __launch_bounds__(256) void k1_gram(const float* __restrict__ W,
                                               float* __restrict__ psum,
                                               float* __restrict__ prow,
                                               int nch, int td) {
    // union: tile[32][68] (2176 floats) while streaming, then red[4][1024]
    __shared__ __align__(16) float lds[4096];
    float (*tile)[TDIP] = (float(*)[TDIP])lds;

    const int bid  = blockIdx.x;
    const int g    = bid / nch;
    const int ch   = bid - g * nch;
    const int tid  = threadIdx.x;
    const int lane = tid & 63;
    const int wave = tid >> 6;
    const float* Zg = W + (size_t)g * C * D + (size_t)ch * td;

    // lane -> output rows {cq+8a} x {eq+8b}
    const int cq = (lane >> 3) & 7;
    const int eq = lane & 7;
    // staging: thread handles rows r0 and r0+16, float4 group cg
    const int r0 = tid >> 4;   // 0..15
    const int cg = tid & 15;   // 0..15 -> cols cg*4..cg*4+3

    float acc[4][4];
#pragma unroll
    for (int a = 0; a < 4; ++a)
#pragma unroll
        for (int b = 0; b < 4; ++b) acc[a][b] = 0.f;
    float rs0 = 0.f, rs1 = 0.f;

    const int nst = td >> 6;
    for (int st = 0; st < nst; ++st) {
        __syncthreads();   // protect tile reuse
        const float* src = Zg + (size_t)st * TDI + cg * 4;
        float4 v0 = *(const float4*)(src + (size_t)r0 * D);
        float4 v1 = *(const float4*)(src + (size_t)(r0 + 16) * D);
        *(float4*)&tile[r0][cg * 4]      = v0;
        *(float4*)&tile[r0 + 16][cg * 4] = v1;
        rs0 += v0.x + v0.y + v0.z + v0.w;
        rs1 += v1.x + v1.y + v1.z + v1.w;
        __syncthreads();
        // wave w consumes cols [w*16, w*16+16) of the sub-tile
#pragma unroll
        for (int j = 0; j < 4; ++j) {
            const int d0 = wave * 16 + j * 4;
            float4 zc[4], ze[4];
#pragma unroll
            for (int i = 0; i < 4; ++i) zc[i] = *(const float4*)&tile[cq + 8 * i][d0];
#pragma unroll
            for (int i = 0; i < 4; ++i) ze[i] = *(const float4*)&tile[eq + 8 * i][d0];
#pragma unroll
            for (int a = 0; a < 4; ++a)
#pragma unroll
                for (int b = 0; b < 4; ++b) {
                    acc[a][b] = fmaf(zc[a].x, ze[b].x, acc[a][b]);
                    acc[a][b] = fmaf(zc[a].y, ze[b].y, acc[a][b]);
                    acc[a][b] = fmaf(zc[a].z, ze[b].z, acc[a][b]);
                    acc[a][b] = fmaf(zc[a].w, ze[b].w, acc[a][b]);
                }
        }
    }

    // rowsum: 16 consecutive lanes share a row
#pragma unroll
    for (int off = 1; off <= 8; off <<= 1) {
        rs0 += __shfl_xor(rs0, off, 64);
        rs1 += __shfl_xor(rs1, off, 64);
    }

    __syncthreads();   // tile dead; reuse lds as red[4][1024]
#pragma unroll
    for (int a = 0; a < 4; ++a)
#pragma unroll
        for (int b = 0; b < 4; ++b)
            lds[wave * 1024 + (cq + 8 * a) * C + (eq + 8 * b)] = acc[a][b];

    if ((lane & 15) == 0) {
        prow[(size_t)bid * C + r0]      = rs0;
        prow[(size_t)bid * C + r0 + 16] = rs1;
    }

    __syncthreads();
#pragma unroll
    for (int k = 0; k < 4; ++k) {
        int el = tid + 256 * k;
        float s = lds[el] + lds[1024 + el] + lds[2048 + el] + lds[3072 + el];
        psum[(size_t)bid * (C * C) + el] = s;
    }
}

// ---------------------------------------------------------------------------
// K2: per group: S = sum(partials) - D*m*m^T + EPS*I; normalize by Frobenius;
//     5 Newton-Schulz iterations; emit M^T (= (B/sqrt(norm))^T) and v = M*m.
// ---------------------------------------------------------------------------
__global__ __launch_bounds__(256) void k2_ns(const float* __restrict__ psum,
                                             const float* __restrict__ prow,
                                             float* __restrict__ MT,
                                             float* __restrict__ vout,
                                             int nch) {
    __shared__ float S[C][C + 1];
    __shared__ float B[C][C + 1];
    __shared__ float T1[C][C + 1];
    __shared__ float T2[C][C + 1];
    __shared__ float mean[C];
    __shared__ float redw[4];
    __shared__ float normsh;

    const int g   = blockIdx.x;
    const int tid = threadIdx.x;
    const int e   = tid & 31;
    const int cb  = tid >> 5;   // c = cb + 8k

    float selt[4];
#pragma unroll
    for (int k = 0; k < 4; ++k) {
        int el = tid + 256 * k;
        float s = 0.f;
        for (int ch = 0; ch < nch; ++ch)
            s += psum[((size_t)g * nch + ch) * (C * C) + el];
        selt[k] = s;
    }
    if (tid < C) {
        float s = 0.f;
        for (int ch = 0; ch < nch; ++ch)
            s += prow[((size_t)g * nch + ch) * C + tid];
        mean[tid] = s / (float)D;
    }
    __syncthreads();

    float ss = 0.f;
#pragma unroll
    for (int k = 0; k < 4; ++k) {
        int el = tid + 256 * k;
        int c = el >> 5;
        float sv = selt[k] - (float)D * mean[c] * mean[e];
        if (c == e) sv += EPS;
        S[c][e] = sv;
        ss = fmaf(sv, sv, ss);
    }
#pragma unroll
    for (int off = 32; off >= 1; off >>= 1) ss += __shfl_xor(ss, off, 64);
    if ((tid & 63) == 0) redw[tid >> 6] = ss;
    __syncthreads();
    if (tid == 0) normsh = sqrtf(redw[0] + redw[1] + redw[2] + redw[3]);
    __syncthreads();
    const float inv_norm = 1.0f / normsh;
#pragma unroll
    for (int k = 0; k < 4; ++k) {
        int c = cb + 8 * k;
        S[c][e] *= inv_norm;
        B[c][e] = (c == e) ? 1.f : 0.f;
    }
    __syncthreads();

    for (int it = 0; it < NS_ITERS; ++it) {
#pragma unroll
        for (int k = 0; k < 4; ++k) {
            int c = cb + 8 * k;
            float s = 0.f;
            for (int kk = 0; kk < C; ++kk)
                s = fmaf(B[c][kk], B[kk][e], s);
            T1[c][e] = s;
        }
        __syncthreads();
#pragma unroll
        for (int k = 0; k < 4; ++k) {
            int c = cb + 8 * k;
            float s = 0.f;
            for (int kk = 0; kk < C; ++kk)
                s = fmaf(T1[c][kk], B[kk][e], s);
            T2[c][e] = s;
        }
        __syncthreads();
        float pv[4];
#pragma unroll
        for (int k = 0; k < 4; ++k) {
            int c = cb + 8 * k;
            float s = 0.f;
            for (int kk = 0; kk < C; ++kk)
                s = fmaf(T2[c][kk], S[kk][e], s);
            pv[k] = s;
        }
#pragma unroll
        for (int k = 0; k < 4; ++k) {
            int c = cb + 8 * k;
            B[c][e] = 1.5f * B[c][e] - 0.5f * pv[k];
        }
        __syncthreads();
    }

    const float invs = 1.0f / sqrtf(normsh);
#pragma unroll
    for (int k = 0; k < 4; ++k) {
        int c = cb + 8 * k;
        MT[(size_t)g * (C * C) + e * C + c] = B[c][e] * invs;
    }
    if (tid < C) {
        float s = 0.f;
        for (int ee = 0; ee < C; ++ee)
            s = fmaf(B[tid][ee] * invs, mean[ee], s);
        vout[(size_t)g * C + tid] = s;
    }
}

// ---------------------------------------------------------------------------
// K3: W_out = M * Z - v * 1^T   (per group), 2 cols per thread (float2)
// ---------------------------------------------------------------------------
__global__ __launch_bounds__(256) void k3_apply(const float* __restrict__ W,
                                                const float* __restrict__ MT,
                                                const float* __restrict__ vv,
                                                float* __restrict__ out) {
    const int blocksPerGroup = D / 512;     // 36
    const int g  = blockIdx.x / blocksPerGroup;
    const int cb = blockIdx.x % blocksPerGroup;
    const int d0 = cb * 512 + (int)threadIdx.x * 2;
    const float* Zg = W + (size_t)g * C * D + d0;
    const float* Mg = MT + (size_t)g * (C * C);

    float accx[C], accy[C];
#pragma unroll
    for (int r = 0; r < C; ++r) { accx[r] = 0.f; accy[r] = 0.f; }

    for (int e = 0; e < C; ++e) {
        float2 z = *(const float2*)(Zg + (size_t)e * D);
#pragma unroll
        for (int r = 0; r < C; ++r) {
            float m = Mg[e * C + r];   // wave-uniform -> scalar load
            accx[r] = fmaf(m, z.x, accx[r]);
            accy[r] = fmaf(m, z.y, accy[r]);
        }
    }

    float* Og = out + (size_t)g * C * D + d0;
#pragma unroll
    for (int r = 0; r < C; ++r) {
        float vr = vv[g * C + r];      // wave-uniform
        float2 o = make_float2(accx[r] - vr, accy[r] - vr);
        *(float2*)(Og + (size_t)r * D) = o;
    }
}

extern "C" void kernel_launch(void* const* d_in, const int* in_sizes, int n_in,
                              void* d_out, int out_size, void* d_ws, size_t ws_size,
                              hipStream_t stream) {
    const float* w = (const float*)d_in[0];
    float* out = (float*)d_out;

    // prefer 36 chunks (2304 blocks = 9/CU exact); fall back if ws too small
    size_t need36 = ((size_t)G * 36 * (C * C + C) + (size_t)G * (C * C + C)) * sizeof(float);
    const int nch = (ws_size >= need36) ? 36 : 18;
    const int td  = D / nch;

    float* psum = (float*)d_ws;                          // G*nch*1024 floats
    float* prow = psum + (size_t)(G * nch) * (C * C);    // G*nch*32
    float* MT   = prow + (size_t)(G * nch) * C;          // G*1024
    float* vv   = MT   + (size_t)G * (C * C);            // G*32

    k1_gram <<<G * nch, 256, 0, stream>>>(w, psum, prow, nch, td);
    k2_ns   <<<G,       256, 0, stream>>>(psum, prow, MT, vv, nch);
    k3_apply<<<G * (D / 512), 256, 0, stream>>>(w, MT, vv, out);
}

// Round 3
// 96.007 us; speedup vs baseline: 1.6803x; 1.6803x over previous
//
#include <hip/hip_runtime.h>

#define G 64
#define C 32
#define D 18432
#define NCH 16          // chunks per group: 1024 blocks = 4/CU exact (compile-time!)
#define TD 1152         // cols per chunk (NCH*TD == D)
#define KSUB 128        // cols per LDS subtile
#define PSTR 136        // padded bf16 row stride (272 B -> uniform banking)
#define PLANE (32 * PSTR)
#define EPS 1e-5f
#define NS_ITERS 5

typedef __attribute__((ext_vector_type(8))) short short8v;
typedef __attribute__((ext_vector_type(4))) float float4v;

__device__ __forceinline__ void split3(float x, unsigned short& h1,
                                       unsigned short& h2, unsigned short& h3) {
    unsigned int u = __float_as_uint(x);
    unsigned int m1 = u & 0xffff0000u;
    float r1 = x - __uint_as_float(m1);
    unsigned int u2 = __float_as_uint(r1);
    unsigned int m2 = u2 & 0xffff0000u;
    float r2 = r1 - __uint_as_float(m2);
    h1 = (unsigned short)(m1 >> 16);
    h2 = (unsigned short)(m2 >> 16);
    h3 = (unsigned short)(__float_as_uint(r2) >> 16);
}

// ---------------------------------------------------------------------------
// K1: per (group, chunk): partial Gram P = Z_chunk * Z_chunk^T via bf16 MFMA
//     with 3-term split (fp32-accurate), plus partial row sums. Deterministic.
// ---------------------------------------------------------------------------
__global__ __launch_bounds__(256) void k1_gram(const float* __restrict__ W,
                                               float* __restrict__ psum,
                                               float* __restrict__ prow) {
    // planes: 3 x [32][PSTR] bf16 = 26112 B; reused as red[4][32][33] f32 (16896 B)
    __shared__ __align__(16) unsigned short lds_u[3 * PLANE];

    const int bid  = blockIdx.x;
    const int g    = bid >> 4;          // / NCH
    const int ch   = bid & 15;          // % NCH
    const int tid  = threadIdx.x;
    const int lane = tid & 63;
    const int wave = tid >> 6;
    const float* Zg = W + (size_t)g * C * D + (size_t)ch * TD;

    // staging: thread owns row r, 16 cols starting at cb (per subtile)
    const int r  = tid >> 3;            // 0..31
    const int cb = (tid & 7) * 16;      // 0,16,...,112
    const float* srcRow = Zg + (size_t)r * D;

    // compute: fragment geometry for mfma_f32_16x16x32_bf16
    const int lh = lane & 15;           // row-in-half (A) == col-in-half (B)
    const int kb = (lane >> 4) * 8;     // k offset within 32-k step
    const int kbase = wave * 32;        // each wave owns 32 of the 128 cols

    float4v acc[2][2];
#pragma unroll
    for (int a = 0; a < 2; ++a)
#pragma unroll
        for (int b = 0; b < 2; ++b) acc[a][b] = (float4v)0.f;
    float rs = 0.f;

    for (int st = 0; st < TD / KSUB; ++st) {
        __syncthreads();   // waves finished reading previous subtile
        // ---- stage: load 16 fp32, split to 3 bf16 planes ----
        const float* s = srcRow + st * KSUB + cb;
        float x[16];
#pragma unroll
        for (int i = 0; i < 4; ++i) {
            float4 v = *(const float4*)(s + i * 4);
            x[4 * i + 0] = v.x; x[4 * i + 1] = v.y;
            x[4 * i + 2] = v.z; x[4 * i + 3] = v.w;
        }
        unsigned short h1[16], h2[16], h3[16];
#pragma unroll
        for (int i = 0; i < 16; ++i) {
            rs += x[i];
            split3(x[i], h1[i], h2[i], h3[i]);
        }
        const int widx = r * PSTR + cb;
#pragma unroll
        for (int q = 0; q < 2; ++q) {
            short8v v1, v2, v3;
#pragma unroll
            for (int j = 0; j < 8; ++j) {
                v1[j] = (short)h1[8 * q + j];
                v2[j] = (short)h2[8 * q + j];
                v3[j] = (short)h3[8 * q + j];
            }
            *(short8v*)&lds_u[widx + 8 * q]             = v1;
            *(short8v*)&lds_u[PLANE + widx + 8 * q]     = v2;
            *(short8v*)&lds_u[2 * PLANE + widx + 8 * q] = v3;
        }
        __syncthreads();
        // ---- compute: 6 fragment reads, 24 MFMAs (6 split-products x 4 tiles) ----
        short8v fr[2][3];
#pragma unroll
        for (int h = 0; h < 2; ++h)
#pragma unroll
            for (int p = 0; p < 3; ++p)
                fr[h][p] = *(const short8v*)&lds_u[p * PLANE + (16 * h + lh) * PSTR + kbase + kb];
#pragma unroll
        for (int a = 0; a < 2; ++a)
#pragma unroll
            for (int b = 0; b < 2; ++b) {
                float4v t = acc[a][b];
                t = __builtin_amdgcn_mfma_f32_16x16x32_bf16(fr[a][0], fr[b][0], t, 0, 0, 0);
                t = __builtin_amdgcn_mfma_f32_16x16x32_bf16(fr[a][0], fr[b][1], t, 0, 0, 0);
                t = __builtin_amdgcn_mfma_f32_16x16x32_bf16(fr[a][1], fr[b][0], t, 0, 0, 0);
                t = __builtin_amdgcn_mfma_f32_16x16x32_bf16(fr[a][1], fr[b][1], t, 0, 0, 0);
                t = __builtin_amdgcn_mfma_f32_16x16x32_bf16(fr[a][0], fr[b][2], t, 0, 0, 0);
                t = __builtin_amdgcn_mfma_f32_16x16x32_bf16(fr[a][2], fr[b][0], t, 0, 0, 0);
                acc[a][b] = t;
            }
    }

    // ---- rowsum: 8 consecutive lanes share a row ----
#pragma unroll
    for (int off = 1; off <= 4; off <<= 1) rs += __shfl_xor(rs, off, 64);
    if ((tid & 7) == 0) prow[(size_t)bid * C + r] = rs;

    // ---- cross-wave Gram reduction (reuse LDS as red[4][32][33] f32) ----
    __syncthreads();
    float* red = (float*)lds_u;
#pragma unroll
    for (int a = 0; a < 2; ++a)
#pragma unroll
        for (int b = 0; b < 2; ++b)
#pragma unroll
            for (int j = 0; j < 4; ++j) {
                int row = 16 * a + ((lane >> 4) << 2) + j;   // m89-verified C/D map
                int col = 16 * b + lh;
                red[wave * 1056 + row * 33 + col] = acc[a][b][j];
            }
    __syncthreads();
#pragma unroll
    for (int k = 0; k < 4; ++k) {
        int el = tid + 256 * k;
        int row = el >> 5, col = el & 31;
        int o = row * 33 + col;
        float sv = red[o] + red[1056 + o] + red[2112 + o] + red[3168 + o];
        psum[(size_t)bid * (C * C) + el] = sv;
    }
}

// ---------------------------------------------------------------------------
// K2: per group: S = sum(partials) - D*m*m^T + EPS*I; Frobenius-normalize;
//     5 Newton-Schulz iterations; emit M^T and v = M*m.  (compile-time NCH)
// ---------------------------------------------------------------------------
__global__ __launch_bounds__(256) void k2_ns(const float* __restrict__ psum,
                                             const float* __restrict__ prow,
                                             float* __restrict__ MT,
                                             float* __restrict__ vout) {
    __shared__ float S[C][C + 1];
    __shared__ float B[C][C + 1];
    __shared__ float T1[C][C + 1];
    __shared__ float T2[C][C + 1];
    __shared__ float mean[C];
    __shared__ float redw[4];
    __shared__ float normsh;

    const int g   = blockIdx.x;
    const int tid = threadIdx.x;
    const int e   = tid & 31;
    const int cb  = tid >> 5;

    float selt[4];
#pragma unroll
    for (int k = 0; k < 4; ++k) {
        int el = tid + 256 * k;
        float s = 0.f;
#pragma unroll
        for (int ch = 0; ch < NCH; ++ch)
            s += psum[((size_t)g * NCH + ch) * (C * C) + el];
        selt[k] = s;
    }
    if (tid < C) {
        float s = 0.f;
#pragma unroll
        for (int ch = 0; ch < NCH; ++ch)
            s += prow[((size_t)g * NCH + ch) * C + tid];
        mean[tid] = s / (float)D;
    }
    __syncthreads();

    float ss = 0.f;
#pragma unroll
    for (int k = 0; k < 4; ++k) {
        int el = tid + 256 * k;
        int c = el >> 5;
        float sv = selt[k] - (float)D * mean[c] * mean[e];
        if (c == e) sv += EPS;
        S[c][e] = sv;
        ss = fmaf(sv, sv, ss);
    }
#pragma unroll
    for (int off = 32; off >= 1; off >>= 1) ss += __shfl_xor(ss, off, 64);
    if ((tid & 63) == 0) redw[tid >> 6] = ss;
    __syncthreads();
    if (tid == 0) normsh = sqrtf(redw[0] + redw[1] + redw[2] + redw[3]);
    __syncthreads();
    const float inv_norm = 1.0f / normsh;
#pragma unroll
    for (int k = 0; k < 4; ++k) {
        int c = cb + 8 * k;
        S[c][e] *= inv_norm;
        B[c][e] = (c == e) ? 1.f : 0.f;
    }
    __syncthreads();

    for (int it = 0; it < NS_ITERS; ++it) {
#pragma unroll
        for (int k = 0; k < 4; ++k) {
            int c = cb + 8 * k;
            float s = 0.f;
            for (int kk = 0; kk < C; ++kk)
                s = fmaf(B[c][kk], B[kk][e], s);
            T1[c][e] = s;
        }
        __syncthreads();
#pragma unroll
        for (int k = 0; k < 4; ++k) {
            int c = cb + 8 * k;
            float s = 0.f;
            for (int kk = 0; kk < C; ++kk)
                s = fmaf(T1[c][kk], B[kk][e], s);
            T2[c][e] = s;
        }
        __syncthreads();
        float pv[4];
#pragma unroll
        for (int k = 0; k < 4; ++k) {
            int c = cb + 8 * k;
            float s = 0.f;
            for (int kk = 0; kk < C; ++kk)
                s = fmaf(T2[c][kk], S[kk][e], s);
            pv[k] = s;
        }
#pragma unroll
        for (int k = 0; k < 4; ++k) {
            int c = cb + 8 * k;
            B[c][e] = 1.5f * B[c][e] - 0.5f * pv[k];
        }
        __syncthreads();
    }

    const float invs = 1.0f / sqrtf(normsh);
#pragma unroll
    for (int k = 0; k < 4; ++k) {
        int c = cb + 8 * k;
        MT[(size_t)g * (C * C) + e * C + c] = B[c][e] * invs;
    }
    if (tid < C) {
        float s = 0.f;
        for (int ee = 0; ee < C; ++ee)
            s = fmaf(B[tid][ee] * invs, mean[ee], s);
        vout[(size_t)g * C + tid] = s;
    }
}

// ---------------------------------------------------------------------------
// K3: W_out = M * Z - v * 1^T   (per group), 2 cols per thread (float2)
// ---------------------------------------------------------------------------
__global__ __launch_bounds__(256) void k3_apply(const float* __restrict__ W,
                                                const float* __restrict__ MT,
                                                const float* __restrict__ vv,
                                                float* __restrict__ out) {
    const int blocksPerGroup = D / 512;     // 36
    const int g  = blockIdx.x / blocksPerGroup;
    const int cbk = blockIdx.x % blocksPerGroup;
    const int d0 = cbk * 512 + (int)threadIdx.x * 2;
    const float* Zg = W + (size_t)g * C * D + d0;
    const float* Mg = MT + (size_t)g * (C * C);

    float accx[C], accy[C];
#pragma unroll
    for (int r = 0; r < C; ++r) { accx[r] = 0.f; accy[r] = 0.f; }

    for (int e = 0; e < C; ++e) {
        float2 z = *(const float2*)(Zg + (size_t)e * D);
#pragma unroll
        for (int r = 0; r < C; ++r) {
            float m = Mg[e * C + r];   // wave-uniform -> scalar load
            accx[r] = fmaf(m, z.x, accx[r]);
            accy[r] = fmaf(m, z.y, accy[r]);
        }
    }

    float* Og = out + (size_t)g * C * D + d0;
#pragma unroll
    for (int r = 0; r < C; ++r) {
        float vr = vv[g * C + r];      // wave-uniform
        float2 o = make_float2(accx[r] - vr, accy[r] - vr);
        *(float2*)(Og + (size_t)r * D) = o;
    }
}

extern "C" void kernel_launch(void* const* d_in, const int* in_sizes, int n_in,
                              void* d_out, int out_size, void* d_ws, size_t ws_size,
                              hipStream_t stream) {
    const float* w = (const float*)d_in[0];
    float* out = (float*)d_out;

    float* psum = (float*)d_ws;                          // G*NCH*1024 floats (4 MB)
    float* prow = psum + (size_t)(G * NCH) * (C * C);    // G*NCH*32
    float* MT   = prow + (size_t)(G * NCH) * C;          // G*1024
    float* vv   = MT   + (size_t)G * (C * C);            // G*32

    k1_gram <<<G * NCH, 256, 0, stream>>>(w, psum, prow);
    k2_ns   <<<G,       256, 0, stream>>>(psum, prow, MT, vv);
    k3_apply<<<G * (D / 512), 256, 0, stream>>>(w, MT, vv, out);
}